// Round 1
// baseline (1242.131 us; speedup 1.0000x reference)
//
#include <hip/hip_runtime.h>
#include <hip/hip_bf16.h>
#include <math.h>

// KGATConv: N=50000 nodes, E=800000 edges, D=64, R=16 relations, fp32.
// Pipeline: proj GEMMs -> per-edge att + segmax -> exp + denom -> scatter -> bi-interaction.

#define DIM 64

__device__ __forceinline__ float4 f4fma(const float4 w, const float s, float4 acc) {
    acc.x = fmaf(w.x, s, acc.x);
    acc.y = fmaf(w.y, s, acc.y);
    acc.z = fmaf(w.z, s, acc.z);
    acc.w = fmaf(w.w, s, acc.w);
    return acc;
}

__device__ __forceinline__ float4 f4zero() { return make_float4(0.f, 0.f, 0.f, 0.f); }

// ---------------------------------------------------------------------------
// proj[r,n,e] = sum_d nfeat[n,d] * relW[r,d,e]
// Block: 256 threads handle a 64-node x 64-col tile for one relation r.
// Thread (cidx = tx&15, q = tx>>4) computes 4 nodes (4q..4q+3) x 4 cols (float4).
// ---------------------------------------------------------------------------
__global__ __launch_bounds__(256) void k_proj(const float* __restrict__ nfeat,
                                              const float* __restrict__ relW,
                                              float* __restrict__ proj,
                                              int N) {
    __shared__ float4 shW[64 * 16];    // [d][cidx], 16 KiB; 2-way bank alias = free
    __shared__ float4 shNF[64 * 17];   // [node][cidx], stride 17 to break bank stride

    const int tx = threadIdx.x;
    const int r = blockIdx.y;
    const int n0 = blockIdx.x * 64;

    const float4* Wr = (const float4*)(relW + (size_t)r * DIM * DIM);
#pragma unroll
    for (int i = 0; i < 4; ++i) shW[tx + 256 * i] = Wr[tx + 256 * i];

    const float4* nf4 = (const float4*)(nfeat + (size_t)n0 * DIM);
#pragma unroll
    for (int i = 0; i < 4; ++i) {
        int idx = tx + 256 * i;            // 0..1023 = 64 rows x 16 f4-cols
        int row = idx >> 4, c = idx & 15;
        float4 v = (n0 + row < N) ? nf4[idx] : f4zero();
        shNF[row * 17 + c] = v;
    }
    __syncthreads();

    const int cidx = tx & 15;
    const int q4 = (tx >> 4) * 4;          // first of 4 node rows this thread owns

    float4 acc[4] = {f4zero(), f4zero(), f4zero(), f4zero()};
#pragma unroll
    for (int d0 = 0; d0 < 64; d0 += 4) {
        float4 w0 = shW[(d0 + 0) * 16 + cidx];
        float4 w1 = shW[(d0 + 1) * 16 + cidx];
        float4 w2 = shW[(d0 + 2) * 16 + cidx];
        float4 w3 = shW[(d0 + 3) * 16 + cidx];
#pragma unroll
        for (int k = 0; k < 4; ++k) {
            float4 nf = shNF[(q4 + k) * 17 + (d0 >> 2)];
            acc[k] = f4fma(w0, nf.x, acc[k]);
            acc[k] = f4fma(w1, nf.y, acc[k]);
            acc[k] = f4fma(w2, nf.z, acc[k]);
            acc[k] = f4fma(w3, nf.w, acc[k]);
        }
    }

    float4* outp = (float4*)(proj + ((size_t)r * N + n0) * DIM);
#pragma unroll
    for (int k = 0; k < 4; ++k) {
        int node = q4 + k;
        if (n0 + node < N) outp[node * 16 + cidx] = acc[k];
    }
}

// ---------------------------------------------------------------------------
// att[e] = dot(proj[r*N+src], tanh(proj[r*N+dst] + efeat[e])); segmax via
// atomicMax on order-preserving uint keys. One wave (64 lanes) per edge.
// ---------------------------------------------------------------------------
__global__ __launch_bounds__(256) void k_att(const float* __restrict__ proj,
                                             const float* __restrict__ efeat,
                                             const int* __restrict__ src,
                                             const int* __restrict__ dst,
                                             const int* __restrict__ etype,
                                             float* __restrict__ att,
                                             unsigned* __restrict__ segmax,
                                             int N, int E) {
    int e = blockIdx.x * 4 + (threadIdx.x >> 6);
    if (e >= E) return;
    int lane = threadIdx.x & 63;
    int s = src[e], d = dst[e], r = etype[e];

    float t = proj[((size_t)r * N + s) * DIM + lane];
    float h = proj[((size_t)r * N + d) * DIM + lane];
    float ef = efeat[(size_t)e * DIM + lane];
    float v = t * tanhf(h + ef);
#pragma unroll
    for (int m = 32; m; m >>= 1) v += __shfl_xor(v, m);
    if (lane == 0) {
        att[e] = v;
        unsigned bits = __float_as_uint(v);
        unsigned key = bits ^ (unsigned)(((int)bits >> 31) | 0x80000000);
        atomicMax(&segmax[d], key);
    }
}

// ---------------------------------------------------------------------------
// ex[e] = exp(att - segmax[dst]); denom[dst] += ex.  Thread per edge.
// ---------------------------------------------------------------------------
__global__ __launch_bounds__(256) void k_exden(const float* __restrict__ att,
                                               const int* __restrict__ dst,
                                               const unsigned* __restrict__ segmax,
                                               float* __restrict__ ex,
                                               float* __restrict__ denom,
                                               int E) {
    int e = blockIdx.x * 256 + threadIdx.x;
    if (e >= E) return;
    int d = dst[e];
    unsigned key = segmax[d];
    unsigned bits = (key & 0x80000000u) ? (key ^ 0x80000000u) : ~key;
    float m = __uint_as_float(bits);
    float x = expf(att[e] - m);
    ex[e] = x;
    atomicAdd(&denom[d], x);
}

// ---------------------------------------------------------------------------
// h_neighbor[dst] += (ex/denom[dst]) * nfeat[src].  One wave per edge,
// 64 fp32 atomics per edge.
// ---------------------------------------------------------------------------
__global__ __launch_bounds__(256) void k_scatter(const float* __restrict__ ex,
                                                 const float* __restrict__ denom,
                                                 const float* __restrict__ nfeat,
                                                 const int* __restrict__ src,
                                                 const int* __restrict__ dst,
                                                 float* __restrict__ hn,
                                                 int E) {
    int e = blockIdx.x * 4 + (threadIdx.x >> 6);
    if (e >= E) return;
    int lane = threadIdx.x & 63;
    int s = src[e], d = dst[e];
    float a = ex[e] / denom[d];
    atomicAdd(&hn[(size_t)d * DIM + lane], a * nfeat[(size_t)s * DIM + lane]);
}

// ---------------------------------------------------------------------------
// out = lrelu((nfeat+hn)@W1) + lrelu((nfeat*hn)@W2).  Same tile shape as k_proj.
// ---------------------------------------------------------------------------
__global__ __launch_bounds__(256) void k_bi(const float* __restrict__ nfeat,
                                            const float* __restrict__ hn,
                                            const float* __restrict__ W1,
                                            const float* __restrict__ W2,
                                            float* __restrict__ out,
                                            int N) {
    __shared__ float4 shW1[64 * 16];
    __shared__ float4 shW2[64 * 16];
    __shared__ float4 shV1[64 * 17];
    __shared__ float4 shV2[64 * 17];

    const int tx = threadIdx.x;
    const int n0 = blockIdx.x * 64;

#pragma unroll
    for (int i = 0; i < 4; ++i) {
        shW1[tx + 256 * i] = ((const float4*)W1)[tx + 256 * i];
        shW2[tx + 256 * i] = ((const float4*)W2)[tx + 256 * i];
    }
    const float4* nf4 = (const float4*)(nfeat + (size_t)n0 * DIM);
    const float4* hn4 = (const float4*)(hn + (size_t)n0 * DIM);
#pragma unroll
    for (int i = 0; i < 4; ++i) {
        int idx = tx + 256 * i;
        int row = idx >> 4, c = idx & 15;
        float4 a = f4zero(), b = f4zero();
        if (n0 + row < N) { a = nf4[idx]; b = hn4[idx]; }
        float4 v1, v2;
        v1.x = a.x + b.x; v1.y = a.y + b.y; v1.z = a.z + b.z; v1.w = a.w + b.w;
        v2.x = a.x * b.x; v2.y = a.y * b.y; v2.z = a.z * b.z; v2.w = a.w * b.w;
        shV1[row * 17 + c] = v1;
        shV2[row * 17 + c] = v2;
    }
    __syncthreads();

    const int cidx = tx & 15;
    const int q4 = (tx >> 4) * 4;

    float4 acc1[4] = {f4zero(), f4zero(), f4zero(), f4zero()};
    float4 acc2[4] = {f4zero(), f4zero(), f4zero(), f4zero()};
#pragma unroll
    for (int d0 = 0; d0 < 64; d0 += 4) {
        float4 a0 = shW1[(d0 + 0) * 16 + cidx];
        float4 a1 = shW1[(d0 + 1) * 16 + cidx];
        float4 a2 = shW1[(d0 + 2) * 16 + cidx];
        float4 a3 = shW1[(d0 + 3) * 16 + cidx];
        float4 b0 = shW2[(d0 + 0) * 16 + cidx];
        float4 b1 = shW2[(d0 + 1) * 16 + cidx];
        float4 b2 = shW2[(d0 + 2) * 16 + cidx];
        float4 b3 = shW2[(d0 + 3) * 16 + cidx];
#pragma unroll
        for (int k = 0; k < 4; ++k) {
            float4 v1 = shV1[(q4 + k) * 17 + (d0 >> 2)];
            float4 v2 = shV2[(q4 + k) * 17 + (d0 >> 2)];
            acc1[k] = f4fma(a0, v1.x, acc1[k]);
            acc1[k] = f4fma(a1, v1.y, acc1[k]);
            acc1[k] = f4fma(a2, v1.z, acc1[k]);
            acc1[k] = f4fma(a3, v1.w, acc1[k]);
            acc2[k] = f4fma(b0, v2.x, acc2[k]);
            acc2[k] = f4fma(b1, v2.y, acc2[k]);
            acc2[k] = f4fma(b2, v2.z, acc2[k]);
            acc2[k] = f4fma(b3, v2.w, acc2[k]);
        }
    }

    float4* outp = (float4*)(out + (size_t)n0 * DIM);
#pragma unroll
    for (int k = 0; k < 4; ++k) {
        int node = q4 + k;
        if (n0 + node >= N) continue;
        float4 r1 = acc1[k], r2 = acc2[k], o;
        o.x = (r1.x >= 0.f ? r1.x : 0.01f * r1.x) + (r2.x >= 0.f ? r2.x : 0.01f * r2.x);
        o.y = (r1.y >= 0.f ? r1.y : 0.01f * r1.y) + (r2.y >= 0.f ? r2.y : 0.01f * r2.y);
        o.z = (r1.z >= 0.f ? r1.z : 0.01f * r1.z) + (r2.z >= 0.f ? r2.z : 0.01f * r2.z);
        o.w = (r1.w >= 0.f ? r1.w : 0.01f * r1.w) + (r2.w >= 0.f ? r2.w : 0.01f * r2.w);
        outp[node * 16 + cidx] = o;
    }
}

extern "C" void kernel_launch(void* const* d_in, const int* in_sizes, int n_in,
                              void* d_out, int out_size, void* d_ws, size_t ws_size,
                              hipStream_t stream) {
    const float* nfeat = (const float*)d_in[0];
    const float* efeat = (const float*)d_in[1];
    const float* relW  = (const float*)d_in[2];
    const float* W1    = (const float*)d_in[3];
    const float* W2    = (const float*)d_in[4];
    const int* src   = (const int*)d_in[5];
    const int* dst   = (const int*)d_in[6];
    const int* etype = (const int*)d_in[7];

    const int N = in_sizes[0] / DIM;
    const int E = in_sizes[5];
    const int R = in_sizes[2] / (DIM * DIM);

    float* out = (float*)d_out;
    float* hn  = out;                          // output 0: h_neighbor (N x 64)
    float* bi  = out + (size_t)N * DIM;        // output 1: out (N x 64)

    // ws layout: proj (R*N*64 f32) | att (E) | ex (E) | segmax keys (N u32) | denom (N f32)
    float* proj = (float*)d_ws;
    size_t projElems = (size_t)R * N * DIM;
    float* att = proj + projElems;
    float* ex  = att + E;
    unsigned* segmax = (unsigned*)(ex + E);
    float* denom = (float*)(segmax + N);

    hipMemsetAsync(segmax, 0, (size_t)2 * N * sizeof(float), stream);  // segmax keys + denom
    hipMemsetAsync(hn, 0, (size_t)N * DIM * sizeof(float), stream);    // h_neighbor accumulator

    dim3 gProj((N + 63) / 64, R);
    k_proj<<<gProj, 256, 0, stream>>>(nfeat, relW, proj, N);
    k_att<<<(E + 3) / 4, 256, 0, stream>>>(proj, efeat, src, dst, etype, att, segmax, N, E);
    k_exden<<<(E + 255) / 256, 256, 0, stream>>>(att, dst, segmax, ex, denom, E);
    k_scatter<<<(E + 3) / 4, 256, 0, stream>>>(ex, denom, nfeat, src, dst, hn, E);
    k_bi<<<(N + 63) / 64, 256, 0, stream>>>(nfeat, hn, W1, W2, bi, N);
}

// Round 2
// 1005.612 us; speedup vs baseline: 1.2352x; 1.2352x over previous
//
#include <hip/hip_runtime.h>
#include <hip/hip_bf16.h>
#include <math.h>

// KGATConv: N=50000, E=800000, D=64, R=16, fp32.
// R2: CSR-by-dst + fused online-softmax aggregation + fused bi-interaction
// epilogue (kills the spilling k_bi and all feature-path atomics).

#define DIM 64

__device__ __forceinline__ float4 f4fma(const float4 w, const float s, float4 acc) {
    acc.x = fmaf(w.x, s, acc.x);
    acc.y = fmaf(w.y, s, acc.y);
    acc.z = fmaf(w.z, s, acc.z);
    acc.w = fmaf(w.w, s, acc.w);
    return acc;
}
__device__ __forceinline__ float4 f4zero() { return make_float4(0.f, 0.f, 0.f, 0.f); }

// ---------------------------------------------------------------------------
// proj[r,n,:] = nfeat[n,:] @ relW[r,:,:]   (64-node x 64-col tile per block)
// ---------------------------------------------------------------------------
__global__ __launch_bounds__(256) void k_proj(const float* __restrict__ nfeat,
                                              const float* __restrict__ relW,
                                              float* __restrict__ proj,
                                              int N) {
    __shared__ float4 shW[64 * 16];
    __shared__ float4 shNF[64 * 17];

    const int tx = threadIdx.x;
    const int r = blockIdx.y;
    const int n0 = blockIdx.x * 64;

    const float4* Wr = (const float4*)(relW + (size_t)r * DIM * DIM);
#pragma unroll
    for (int i = 0; i < 4; ++i) shW[tx + 256 * i] = Wr[tx + 256 * i];

    const float4* nf4 = (const float4*)(nfeat + (size_t)n0 * DIM);
#pragma unroll
    for (int i = 0; i < 4; ++i) {
        int idx = tx + 256 * i;
        int row = idx >> 4, c = idx & 15;
        float4 v = (n0 + row < N) ? nf4[idx] : f4zero();
        shNF[row * 17 + c] = v;
    }
    __syncthreads();

    const int cidx = tx & 15;
    const int q4 = (tx >> 4) * 4;

    float4 acc[4] = {f4zero(), f4zero(), f4zero(), f4zero()};
#pragma unroll
    for (int d0 = 0; d0 < 64; d0 += 4) {
        float4 w0 = shW[(d0 + 0) * 16 + cidx];
        float4 w1 = shW[(d0 + 1) * 16 + cidx];
        float4 w2 = shW[(d0 + 2) * 16 + cidx];
        float4 w3 = shW[(d0 + 3) * 16 + cidx];
#pragma unroll
        for (int k = 0; k < 4; ++k) {
            float4 nf = shNF[(q4 + k) * 17 + (d0 >> 2)];
            acc[k] = f4fma(w0, nf.x, acc[k]);
            acc[k] = f4fma(w1, nf.y, acc[k]);
            acc[k] = f4fma(w2, nf.z, acc[k]);
            acc[k] = f4fma(w3, nf.w, acc[k]);
        }
    }

    float4* outp = (float4*)(proj + ((size_t)r * N + n0) * DIM);
#pragma unroll
    for (int k = 0; k < 4; ++k) {
        int node = q4 + k;
        if (n0 + node < N) outp[node * 16 + cidx] = acc[k];
    }
}

// ---------------------------------------------------------------------------
// CSR build: histogram -> single-block scan -> fill
// ---------------------------------------------------------------------------
__global__ __launch_bounds__(256) void k_hist(const int* __restrict__ dst,
                                              int* __restrict__ deg, int E) {
    int e = blockIdx.x * 256 + threadIdx.x;
    if (e < E) atomicAdd(&deg[dst[e]], 1);
}

__global__ __launch_bounds__(1024) void k_scan(const int* __restrict__ deg,
                                               int* __restrict__ off,
                                               int* __restrict__ cursor,
                                               int N, int E) {
    __shared__ int part[1024];
    const int t = threadIdx.x;
    const int chunk = (N + 1023) / 1024;
    const int s0 = t * chunk;
    const int s1 = min(s0 + chunk, N);

    int sum = 0;
    for (int i = s0; i < s1; ++i) sum += deg[i];
    part[t] = sum;
    __syncthreads();
    for (int d = 1; d < 1024; d <<= 1) {
        int other = (t >= d) ? part[t - d] : 0;
        __syncthreads();
        part[t] += other;
        __syncthreads();
    }
    int run = part[t] - sum;  // exclusive prefix of this thread's chunk
    for (int i = s0; i < s1; ++i) {
        off[i] = run;
        cursor[i] = run;
        run += deg[i];
    }
    if (t == 0) off[N] = E;
}

__global__ __launch_bounds__(256) void k_fill(const int* __restrict__ dst,
                                              int* __restrict__ cursor,
                                              int* __restrict__ eidx, int E) {
    int e = blockIdx.x * 256 + threadIdx.x;
    if (e >= E) return;
    int p = atomicAdd(&cursor[dst[e]], 1);
    eidx[p] = e;
}

// ---------------------------------------------------------------------------
// Fused: per-dst online-softmax attention aggregation + bi-interaction.
// One wave (64 lanes) per destination node; lane = feature index.
// ---------------------------------------------------------------------------
__global__ __launch_bounds__(256) void k_agg(const float* __restrict__ proj,
                                             const float* __restrict__ efeat,
                                             const float* __restrict__ nfeat,
                                             const int* __restrict__ src,
                                             const int* __restrict__ etype,
                                             const int* __restrict__ off,
                                             const int* __restrict__ eidx,
                                             const float* __restrict__ W1,
                                             const float* __restrict__ W2,
                                             float* __restrict__ hn,
                                             float* __restrict__ out,
                                             int N) {
    const int node = blockIdx.x * 4 + (threadIdx.x >> 6);
    if (node >= N) return;          // no barriers below; waves independent
    const int lane = threadIdx.x & 63;

    const int jb = off[node];
    const int je = off[node + 1];

    float m = -INFINITY, l = 0.f, acc = 0.f;
    for (int j = jb; j < je; ++j) {
        const int e = eidx[j];
        const int s = src[e];
        const int r = etype[e];
        float t = proj[((size_t)r * N + s) * DIM + lane];
        float h = proj[((size_t)r * N + node) * DIM + lane];
        float ef = efeat[(size_t)e * DIM + lane];
        float v = t * tanhf(h + ef);
#pragma unroll
        for (int ms = 32; ms; ms >>= 1) v += __shfl_xor(v, ms);  // all lanes get sum
        float m_new = fmaxf(m, v);
        float corr = expf(m - m_new);   // first iter: exp(-inf)=0
        float p = expf(v - m_new);
        l = l * corr + p;
        acc = acc * corr + p * nfeat[(size_t)s * DIM + lane];
        m = m_new;
    }

    const float hval = (je > jb) ? acc / l : 0.f;
    hn[(size_t)node * DIM + lane] = hval;

    // Bi-interaction epilogue: out = lrelu((nf+hn)@W1) + lrelu((nf*hn)@W2)
    const float nf = nfeat[(size_t)node * DIM + lane];
    const float v1 = nf + hval;
    const float v2 = nf * hval;
    float o1 = 0.f, o2 = 0.f;
#pragma unroll 8
    for (int d = 0; d < DIM; ++d) {
        float s1 = __shfl(v1, d);
        float s2 = __shfl(v2, d);
        o1 = fmaf(s1, W1[d * DIM + lane], o1);   // coalesced, L1-resident
        o2 = fmaf(s2, W2[d * DIM + lane], o2);
    }
    out[(size_t)node * DIM + lane] =
        (o1 >= 0.f ? o1 : 0.01f * o1) + (o2 >= 0.f ? o2 : 0.01f * o2);
}

extern "C" void kernel_launch(void* const* d_in, const int* in_sizes, int n_in,
                              void* d_out, int out_size, void* d_ws, size_t ws_size,
                              hipStream_t stream) {
    const float* nfeat = (const float*)d_in[0];
    const float* efeat = (const float*)d_in[1];
    const float* relW  = (const float*)d_in[2];
    const float* W1    = (const float*)d_in[3];
    const float* W2    = (const float*)d_in[4];
    const int* src   = (const int*)d_in[5];
    const int* dst   = (const int*)d_in[6];
    const int* etype = (const int*)d_in[7];

    const int N = in_sizes[0] / DIM;
    const int E = in_sizes[5];
    const int R = in_sizes[2] / (DIM * DIM);

    float* out = (float*)d_out;
    float* hn  = out;                      // output 0: h_neighbor (N x 64)
    float* bi  = out + (size_t)N * DIM;    // output 1: out (N x 64)

    // ws: proj (R*N*64 f32) | deg[N] | off[N+1] | cursor[N] | eidx[E]
    float* proj = (float*)d_ws;
    size_t projElems = (size_t)R * N * DIM;
    int* deg    = (int*)(proj + projElems);
    int* off    = deg + N;
    int* cursor = off + (N + 1);
    int* eidx   = cursor + N;

    hipMemsetAsync(deg, 0, (size_t)N * sizeof(int), stream);

    k_hist<<<(E + 255) / 256, 256, 0, stream>>>(dst, deg, E);
    k_scan<<<1, 1024, 0, stream>>>(deg, off, cursor, N, E);
    k_fill<<<(E + 255) / 256, 256, 0, stream>>>(dst, cursor, eidx, E);

    dim3 gProj((N + 63) / 64, R);
    k_proj<<<gProj, 256, 0, stream>>>(nfeat, relW, proj, N);

    k_agg<<<(N + 3) / 4, 256, 0, stream>>>(proj, efeat, nfeat, src, etype,
                                           off, eidx, W1, W2, hn, bi, N);
}